// Round 5
// baseline (14780.574 us; speedup 1.0000x reference)
//
#include <hip/hip_runtime.h>
#include <hip/hip_bf16.h>

#define BATCH 16384
#define WDIM 300
#define TDIM 100
#define TD2 200
#define HDIM 512
#define ESIZE 1024

typedef unsigned short ush;

__device__ __forceinline__ float bf2f(ush u) {
    union { unsigned int i; float f; } v; v.i = ((unsigned int)u) << 16; return v.f;
}
__device__ __forceinline__ float2 bf2x2(unsigned int w) {
    union { unsigned int i; float f; } a, b;
    a.i = w << 16; b.i = w & 0xffff0000u;
    return make_float2(a.f, b.f);
}
__device__ __forceinline__ ush f2bf(float f) {
    union { float f; unsigned int i; } v; v.f = f;
    unsigned int x = v.i;
    return (ush)((x + 0x7fffu + ((x >> 16) & 1u)) >> 16);
}
__device__ __forceinline__ float leaky(float v) { return v >= 0.f ? v : 0.1f * v; }

// ---------------- Kernel A2: one block per batch row, direct global dots ----------------
__global__ __launch_bounds__(256) void kA2(const int* __restrict__ x,
                                           const float* __restrict__ eW,
                                           const float* __restrict__ pdW,
                                           const float* __restrict__ pdb,
                                           float* __restrict__ cat)
{
    const int b = blockIdx.x;
    const int tt = threadIdx.x;
    if (tt >= TD2) return;
    const int half = (tt >= TDIM) ? 1 : 0;
    const int t = tt - TDIM * half;
    const int idx = x[b * 2 + half];
    const float* e = eW + (size_t)idx * WDIM;
    const float* p = pdW + (size_t)t * WDIM;
    float s = 0.f;
    for (int d = 0; d < WDIM; ++d) s += e[d] * p[d];
    cat[(size_t)b * TD2 + tt] = leaky(s + pdb[t]);
}

// ---------------- Kernel B2: one thread per (b,k) ----------------
// grid (B/64, 100), block 64. cat rows in padded LDS; comp_T wave-uniform loads.
__global__ __launch_bounds__(64) void kB2(const float* __restrict__ cat,
                                          const float* __restrict__ compT,
                                          const float* __restrict__ clW,
                                          const float* __restrict__ clb,
                                          float* __restrict__ cv)
{
    __shared__ float cS[64][201];   // stride 201 -> conflict-free
    const int tid = threadIdx.x;
    const int b0 = blockIdx.x * 64;
    const int k = blockIdx.y;

    for (int i = tid; i < 64 * TD2; i += 64) {
        int r = i / TD2, c = i - r * TD2;
        cS[r][c] = cat[(size_t)(b0 + r) * TD2 + c];
    }
    __syncthreads();

    const float* T = compT + (size_t)k * 40000;
    float s = 0.f;
    for (int ch = 0; ch < 4; ++ch) {
        float cj[50];
        #pragma unroll
        for (int j = 0; j < 50; ++j) cj[j] = cS[tid][ch * 50 + j];
        for (int i = 0; i < TD2; ++i) {
            const float* Ti = T + i * TD2 + ch * 50;   // uniform across lanes -> s_load
            float u = 0.f;
            #pragma unroll
            for (int j = 0; j < 50; ++j) u += Ti[j] * cj[j];
            s += cS[tid][i] * u;
        }
    }
    float t2 = 0.f;
    for (int j = 0; j < TD2; ++j) t2 += clW[k * TD2 + j] * cS[tid][j];
    cv[(size_t)(b0 + tid) * TDIM + k] = leaky(s + t2 + clb[k]);
}

// ---------------- Kernel C: l1 + l2 -> unnormalized out (f32!) + ssq ----------------
// grid 512 (btile=32), block 256. h bf16 in LDS; l2_W staged f32 (8-row chunks).
__global__ __launch_bounds__(256) void kC(const float* __restrict__ cv,
                                          const float* __restrict__ l1W,
                                          const float* __restrict__ l1b,
                                          const float* __restrict__ l2W,
                                          const float* __restrict__ l2b,
                                          float* __restrict__ out,
                                          float* __restrict__ ssqg)
{
    __shared__ ush hS[32 * 528];     // 33792 B
    __shared__ float w2F[8 * 516];   // 16512 B (cv tile aliased here first)
    const int tid = threadIdx.x;
    const int b0 = blockIdx.x * 32;

    float* cvS = w2F;  // 3200 floats = 12800 B <= 16512 B
    for (int i = tid; i < 3200; i += 256) cvS[i] = cv[(size_t)b0 * TDIM + i];
    __syncthreads();
    for (int o = tid; o < 32 * HDIM; o += 256) {
        int bl = o & 31, e = o >> 5;
        const float* cr = &cvS[bl * TDIM];
        const float* wr = &l1W[e * TDIM];
        float s = 0.f;
        for (int t = 0; t < TDIM; t += 4) {
            float4 w4 = *(const float4*)&wr[t];
            float4 c4 = *(const float4*)&cr[t];
            s += w4.x * c4.x + w4.y * c4.y + w4.z * c4.z + w4.w * c4.w;
        }
        s = leaky(s + l1b[e]);
        hS[bl * 528 + e] = f2bf(s);
    }
    __syncthreads();

    const int b = tid >> 3, el = tid & 7;
    float ssq = 0.f;
    for (int ec = 0; ec < 128; ++ec) {
        {   // stage 8 rows of l2_W as f32
            const float* src = l2W + (size_t)ec * 8 * HDIM;
            for (int i = tid; i < 1024; i += 256) {
                int r = i >> 7, c4 = (i & 127) * 4;
                *(float4*)&w2F[r * 516 + c4] = *(const float4*)&src[r * HDIM + c4];
            }
        }
        __syncthreads();
        {
            const ush* hr = &hS[b * 528];
            const float* wr2 = &w2F[el * 516];
            float s = 0.f;
            for (int j = 0; j < HDIM; j += 8) {
                uint4 hv = *(const uint4*)&hr[j];
                float4 w0 = *(const float4*)&wr2[j];
                float4 w1 = *(const float4*)&wr2[j + 4];
                float2 h0 = bf2x2(hv.x), h1 = bf2x2(hv.y), h2 = bf2x2(hv.z), h3 = bf2x2(hv.w);
                s += h0.x * w0.x + h0.y * w0.y + h1.x * w0.z + h1.y * w0.w
                   + h2.x * w1.x + h2.y * w1.y + h3.x * w1.z + h3.y * w1.w;
            }
            int eg = ec * 8 + el;
            float v = s + l2b[eg];
            out[(size_t)(b0 + b) * ESIZE + eg] = v;
            ssq += v * v;
        }
        __syncthreads();
    }
    ssq += __shfl_xor(ssq, 1);
    ssq += __shfl_xor(ssq, 2);
    ssq += __shfl_xor(ssq, 4);
    if (el == 0) ssqg[b0 + b] = ssq;
}

// ---------------- Kernel D: normalize f32 rows in place ----------------
// grid 8192 (2 rows each), block 256; 8 floats per thread
__global__ __launch_bounds__(256) void kD(float* __restrict__ out,
                                          const float* __restrict__ ssqg)
{
    const int tid = threadIdx.x;
    const int row = blockIdx.x * 2 + (tid >> 7);
    const int col = (tid & 127) * 8;
    const float r = rsqrtf(ssqg[row]);
    float* p = out + (size_t)row * ESIZE + col;
    float4 v0 = *(float4*)p;
    float4 v1 = *(float4*)(p + 4);
    v0.x *= r; v0.y *= r; v0.z *= r; v0.w *= r;
    v1.x *= r; v1.y *= r; v1.z *= r; v1.w *= r;
    *(float4*)p = v0;
    *(float4*)(p + 4) = v1;
}

extern "C" void kernel_launch(void* const* d_in, const int* in_sizes, int n_in,
                              void* d_out, int out_size, void* d_ws, size_t ws_size,
                              hipStream_t stream) {
    const int*   x    = (const int*)d_in[0];
    // d_in[1] = lengths (unused by reference math)
    const float* eW   = (const float*)d_in[2];
    const float* pdW  = (const float*)d_in[3];
    const float* pdb  = (const float*)d_in[4];
    const float* cT   = (const float*)d_in[5];
    const float* clW  = (const float*)d_in[6];
    const float* clb  = (const float*)d_in[7];
    const float* l1W  = (const float*)d_in[8];
    const float* l1b  = (const float*)d_in[9];
    const float* l2W  = (const float*)d_in[10];
    const float* l2b  = (const float*)d_in[11];
    float* out = (float*)d_out;

    float* cat  = (float*)d_ws;                       // B*200 f32
    float* cv   = cat + (size_t)BATCH * TD2;          // B*100 f32
    float* ssqg = cv + (size_t)BATCH * TDIM;          // B f32

    kA2<<<dim3(BATCH), dim3(256), 0, stream>>>(x, eW, pdW, pdb, cat);
    kB2<<<dim3(BATCH / 64, 100), dim3(64), 0, stream>>>(cat, cT, clW, clb, cv);
    kC<<<dim3(512), dim3(256), 0, stream>>>(cv, l1W, l1b, l2W, l2b, out, ssqg);
    kD<<<dim3(8192), dim3(256), 0, stream>>>(out, ssqg);
}